// Round 9
// baseline (340.141 us; speedup 1.0000x reference)
//
#include <hip/hip_runtime.h>
#include <hip/hip_cooperative_groups.h>

namespace cg = cooperative_groups;

// ErosionLayer: B=16, W=512, ITERS=10, fp32. PASSING numeric recipe (r5..r13,
// absmax 0.02734375): XLA-style greedy FMA via explicit fmaf() at exact sites,
// contract(off) elsewhere, correctly-rounded fp32 div/sqrt. cell_math op order
// is the frozen recipe -- only PROVABLY bit-exact simplifications allowed.
//
// History: r17 353.6 (s/w/v dbuf race fix). r18 322.6 (DCE + HH=8). r19/r20
// REGRESSED: forced VGPR cap 64 < ~100+ live -> scratch spill. r21 303.6:
// interleaved ph2 cut live state to 56-64 actual, no spill, 50.3us/dispatch;
// ~50us (17%) lost at dispatch boundaries. r22 NEUTRAL 301.8: coop gate
// failed -- coop kernel built at __launch_bounds__(512,6) (cap 85) so the
// allocator used >64 VGPR -> occupancy query 3 < 4 -> fallback ran.
//
// r23 (this round): make the coop path selectable.
//  - erosion_coop<1>: 1024 blocks, __launch_bounds__(512,8) (cap 64; natural
//    56-64 so low spill risk) -- spill DETECTED at gate time via
//    hipFuncGetAttributes().localSizeBytes>0 -> reject (no r19/r20 blind cliff).
//  - erosion_coop<2>: 512 blocks x 2 tiles/block sequential,
//    __launch_bounds__(512,4) (cap 128, no spill possible at ~60 natural).
//    Only needs 2 blocks/CU co-resident. Tiles in a group are independent
//    (distinct in/out buffers for terrain and s/w/v); __syncthreads between
//    tiles guards LDS reuse.
//  - Gate: coopAttr -> coop<1> (scratch==0 && mb*CU>=1024) -> coop<2>
//    (scratch==0 && mb*CU>=512) -> proven 5-dispatch fallback (r21, 301.8).
// Kernel body unchanged from r21 (single-barrier loop, j=i-5 deferred ph2).
// Bit-exact in all paths. FINAL skips dead s/w/v stores.
#pragma clang fp contract(off)

constexpr int WW   = 512;
constexpr int NPIX = WW * WW;      // 2^18
constexpr int NTOT = 16 * NPIX;    // 4194304
constexpr int HH   = 8;            // owned rows per block
constexpr int AR   = 16;           // LDS rows [r0-4, r0+11]; terrain-k aliased
constexpr int BR   = 12;           // phase-1 computed rows [r0-2, r0+9]
constexpr int NBLK = 16 * (WW / HH);   // 1024

// FROZEN r5/r6 math (+ r18 provably-bit-exact factor/rY/den removal);
// all terrain reads from an LDS tile with row offset.
__device__ __forceinline__ void cell_math(
    const float* __restrict__ lds, int rowOfs, int r, int c,
    float rain_v, float gno_v,
    float rr, float evapr, float minhd, float heps, float gravr, float sccr,
    float diss, float depo,
    float& s_io, float& w_io, float& v_io, float& t_out, bool fin)
{
    #pragma clang fp contract(off)
    const float CELLW = 0.390625f;            // 200/512, exact

    float t_c = lds[(r - rowOfs) * WW + c];

    float w = fmaf(rr, rain_v, w_io);

    float dx, dy;
    if      (r == 0)      dx = 0.5f * fmaf(t_c, 1.1f, -t_c);
    else if (r == WW - 1) dx = 0.5f * fmaf(t_c, 0.9f, -t_c);
    else dx = 0.5f * (lds[(r + 1 - rowOfs) * WW + c] - lds[(r - 1 - rowOfs) * WW + c]);
    if      (c == 0)      dy = 0.5f * fmaf(t_c, 1.1f, -t_c);
    else if (c == WW - 1) dy = 0.5f * fmaf(t_c, 0.9f, -t_c);
    else dy = 0.5f * (lds[(r - rowOfs) * WW + c + 1] - lds[(r - rowOfs) * WW + c - 1]);

    float mag = sqrtf(fmaf(dx, dx, dy * dy) + 1e-11f);
    // r18 bit-exact DCE: mag >= sqrt(1e-11) = 3.16e-6 > 1e-10, so
    // factor = relu(1e-10 - mag) == 0, rY unused, den = mag + 0 = mag.
    // fmaf(0, rX, dx) == dx (sign-of-zero flip absorbed downstream).
    float fdx = dx / mag;                     // |fdx| <= 1 + ~3ulp
    float fdy = dy / mag;                     // |fdy| <= 1 + ~3ulp

    float fx  = (float)c + (-fdx);
    float fy  = (float)r + (-fdy);
    float x0f = floorf(fx), y0f = floorf(fy);
    float wx1 = fx - x0f;
    float wy1 = fy - y0f;
    int x0 = (int)x0f, y0 = (int)y0f;
    int x1 = x0 + 1,   y1 = y0 + 1;

    bool vx0 = (x0 >= 0) & (x0 < WW);
    bool vx1 = (x1 >= 0) & (x1 < WW);
    bool vy0 = (y0 >= 0) & (y0 < WW);
    bool vy1 = (y1 >= 0) & (y1 < WW);
    int x0c = min(max(x0, 0), WW - 1), x1c = min(max(x1, 0), WW - 1);
    int y0c = min(max(y0, 0), WW - 1), y1c = min(max(y1, 0), WW - 1);
    int ty0 = y0c - rowOfs, ty1 = y1c - rowOfs;   // in [r-2,r+2]-rowOfs

    float g00 = (vx0 && vy0) ? (lds[ty0 * WW + x0c] - 1.0f) : 0.0f;
    float g10 = (vx1 && vy0) ? (lds[ty0 * WW + x1c] - 1.0f) : 0.0f;
    float g01 = (vx0 && vy1) ? (lds[ty1 * WW + x0c] - 1.0f) : 0.0f;
    float g11 = (vx1 && vy1) ? (lds[ty1 * WW + x1c] - 1.0f) : 0.0f;

    float wx0 = 1.0f - wx1;
    float wy0 = 1.0f - wy1;
    float rowA = fmaf(wx0, g00, wx1 * g10);
    float rowB = fmaf(wx0, g01, wx1 * g11);
    float bil  = fmaf(wy0, rowA, wy1 * rowB);
    float neighbor = bil + 1.0f;

    float hd = t_c - neighbor;

    float v = v_io;
    float s = s_io;

    float hds  = ((hd - heps) > 0.0f) ? 1.0f : 0.0f;  // sign(relu(hd-eps))
    float nhd  = hds * fmaxf(hd, minhd);
    float q1 = nhd / CELLW;
    float q2 = q1 * v;
    float q3 = q2 * w;
    float sdiff = fmaf(-q3, sccr, s);                 // s - sed_cap
    float ftb   = (hd < 0.0f) ? 1.0f : 0.0f;          // relu(sign(-hd))
    float first = fminf(fmaxf(-hd, 0.0f), s);
    float ra = fmaxf(sdiff * depo, 0.0f);
    float rb = fmaxf((-sdiff) * diss, 0.0f);
    float deparg = fmaf(1.0f - ftb, ra - rb, first);
    float dep    = fmaxf(-fmaxf(hd, 0.0f), deparg);

    float s_new = s - dep;
    float t_new = t_c + dep;

    float rn = fmaxf(-fdy, 0.0f);
    float rm = fmaxf(1.0f - fabsf(fdy), 0.0f);
    float rp = fmaxf(fdy, 0.0f);

    float s1 = (c == WW - 1) ? 0.0f : rn * s_new;
    float s3 = (c == 0)      ? 0.0f : rp * s_new;
    s_io = fmaf(rm, s_new, s1) + s3;

    float w1 = (c == WW - 1) ? 0.0f : rn * w;
    float w3 = (c == 0)      ? 0.0f : rp * w;
    float wd = fmaf(rm, w, w1) + w3;
    w_io = wd * (1.0f - evapr);

    v_io = (gravr * hd) / CELLW;

    if (fin) {
        float aa = fmaf(-t_new, 2.0f, 1.0f);          // 1 - t*2 -> fnma
        float bq = 1.0f + aa;
        t_out = fmaxf(bq, 0.0f) - 1.0f;
    } else {
        t_out = t_new;
    }
}

// One 2-step group for one block tile. A = 16 LDS rows [r0-4, r0+11];
// phase 1 retires slot i -> terrain-k row r0-2+i; phase 2 deferred j=i-5.
__device__ __forceinline__ void run_group(
    bool FIRST, bool FINAL,
    const float* __restrict__ tb,          // terrain-in image base
    float* __restrict__ tout,
    const float* __restrict__ sed_in, const float* __restrict__ wat_in,
    const float* __restrict__ vel_in,
    float* __restrict__ sed_out, float* __restrict__ wat_out,
    float* __restrict__ vel_out,
    const float* __restrict__ rain0, const float* __restrict__ gno0,
    const float* __restrict__ rain1, const float* __restrict__ gno1,
    float rr, float evapr, float minhd, float heps, float gravr, float sccr,
    float diss, float depo,
    int img, int r0, int c, float* __restrict__ A)
{
    const int gbase = img * NPIX + c;

    // ---- stage terrain k-1 rows [r0-4, r0+11] (float4; transform if FIRST)
    {
        const int rg = c >> 7;               // 0..3
        const int c4 = (c & 127) << 2;       // column start (float4 aligned)
        #pragma unroll
        for (int j = 0; j < 4; ++j) {
            int ridx = j * 4 + rg;           // 0..15, each exactly once
            int y = r0 - 4 + ridx;
            if (y >= 0 && y < WW) {
                float4 v = *reinterpret_cast<const float4*>(tb + y * WW + c4);
                if (FIRST) {
                    v.x = (1.0f - v.x) / 2.0f;
                    v.y = (1.0f - v.y) / 2.0f;
                    v.z = (1.0f - v.z) / 2.0f;
                    v.w = (1.0f - v.w) / 2.0f;
                }
                *reinterpret_cast<float4*>(&A[ridx * WW + c4]) = v;
            }
        }
    }
    __syncthreads();

    // ---- fused loop, ONE barrier per iter. Iter i:
    //  (a) ph1 row x=r0-2+i (reads k-1 slots i..i+4)
    //  (b) barrier
    //  (c) write slot i (terrain-k) ; ph2 row j=i-5 (reads k slots i-5..i-1)
    // Proofs: slot i last k-1-read at (a) of iter i, write at (c) after (b);
    // ph2's newest read (slot i-1, written iter i-1 (c)) separated by (b) of
    // iter i; concurrent iter i+1 (a) reads slots i+1..i+5, disjoint from
    // the slot-i write. sK[j] written iter j+2, read iter j+5.
    float sK[HH], wK[HH], vK[HH];
    #pragma unroll
    for (int i = 0; i < BR; ++i) {
        const int x = r0 - 2 + i;
        const bool live1 = (x >= 0) && (x < WW);   // block-uniform
        float s0 = 0.0f, w0 = 0.0f, v0 = 0.0f, tn = 0.0f;
        if (live1) {
            if (!FIRST) {
                int g = gbase + x * WW;
                s0 = sed_in[g]; w0 = wat_in[g]; v0 = vel_in[g];
            }
            cell_math(A, r0 - 4, x, c, rain0[x * WW + c], gno0[x * WW + c],
                      rr, evapr, minhd, heps, gravr, sccr, diss, depo,
                      s0, w0, v0, tn, false);
        }
        __syncthreads();   // all k-1 reads of slot i complete block-wide
        if (live1) {
            A[i * WW + c] = tn;
            if (i >= 2 && i <= HH + 1) {        // owned rows: j = i-2 (const)
                sK[i - 2] = s0; wK[i - 2] = w0; vK[i - 2] = v0;
            }
        }
        if (i >= 5) {                           // ph2 row j = i-5 (0..6)
            const int j  = i - 5;
            const int x2 = r0 + j;              // always in [0, WW)
            float s2 = sK[j], w2 = wK[j], v2 = vK[j];
            float tn2;
            cell_math(A, r0 - 2, x2, c, rain1[x2 * WW + c], gno1[x2 * WW + c],
                      rr, evapr, minhd, heps, gravr, sccr, diss, depo,
                      s2, w2, v2, tn2, FINAL);
            int g = gbase + x2 * WW;
            tout[g] = tn2;
            if (!FINAL) { sed_out[g] = s2; wat_out[g] = w2; vel_out[g] = v2; }
        }
    }
    __syncthreads();       // slot 11 (written iter 11) visible block-wide

    // ---- epilogue: ph2 row j = 7 (reads k slots 7..11; at r0=504 clamps
    // keep unwritten slots 10,11 unread: y1c<=511 -> slot<=9)
    {
        const int j  = HH - 1;
        const int x2 = r0 + j;
        float s2 = sK[j], w2 = wK[j], v2 = vK[j];
        float tn2;
        cell_math(A, r0 - 2, x2, c, rain1[x2 * WW + c], gno1[x2 * WW + c],
                  rr, evapr, minhd, heps, gravr, sccr, diss, depo,
                  s2, w2, v2, tn2, FINAL);
        int g = gbase + x2 * WW;
        tout[g] = tn2;
        if (!FINAL) { sed_out[g] = s2; wat_out[g] = w2; vel_out[g] = v2; }
    }
}

// ---- fallback kernel: one 2-step group per dispatch (r21, proven 301.8) ----
template <bool FIRST, bool FINAL>
__global__ __launch_bounds__(512, 6) void erosion_step(
    const float* __restrict__ tin, float* __restrict__ tout,
    const float* __restrict__ sed_in, const float* __restrict__ wat_in,
    const float* __restrict__ vel_in,
    float* __restrict__ sed_out, float* __restrict__ wat_out,
    float* __restrict__ vel_out,
    const float* __restrict__ rain0, const float* __restrict__ gno0,
    const float* __restrict__ rain1, const float* __restrict__ gno1,
    const float* __restrict__ s_rain_rate, const float* __restrict__ s_evap,
    const float* __restrict__ s_minhd, const float* __restrict__ s_heps,
    const float* __restrict__ s_grav, const float* __restrict__ s_scc,
    const float* __restrict__ s_diss, const float* __restrict__ s_depo)
{
    #pragma clang fp contract(off)
    __shared__ float A[AR * WW];
    const int c   = threadIdx.x;
    const int img = blockIdx.x >> 6;
    const int r0  = (blockIdx.x & 63) * HH;

    float rr    = fmaxf(s_rain_rate[0], 0.0f);
    float evapr = fmaxf(s_evap[0], 0.0f);
    float minhd = s_minhd[0];
    float heps  = s_heps[0];
    float gravr = fmaxf(s_grav[0], 0.0f);
    float sccr  = fmaxf(s_scc[0], 0.0f);
    float diss  = s_diss[0];
    float depo  = s_depo[0];

    run_group(FIRST, FINAL, tin + (size_t)img * NPIX, tout,
              sed_in, wat_in, vel_in, sed_out, wat_out, vel_out,
              rain0, gno0, rain1, gno1,
              rr, evapr, minhd, heps, gravr, sccr, diss, depo,
              img, r0, c, A);
}

// ---- cooperative kernel: all 5 groups, grid.sync between them.
// NTILE=1: 1024 blocks, cap 64 VGPR (spill checked at gate).
// NTILE=2: 512 blocks x 2 sequential tiles, cap 128 VGPR (no spill).
template <int NTILE>
__global__ __launch_bounds__(512, NTILE == 1 ? 8 : 4) void erosion_coop(
    const float* __restrict__ tin0, float* __restrict__ T0,
    float* __restrict__ T1, float* __restrict__ T2,
    float* __restrict__ sA, float* __restrict__ wA, float* __restrict__ vA,
    float* __restrict__ sB, float* __restrict__ wB, float* __restrict__ vB,
    const float* __restrict__ rain_all, const float* __restrict__ gno_all,
    const float* __restrict__ s_rain_rate, const float* __restrict__ s_evap,
    const float* __restrict__ s_minhd, const float* __restrict__ s_heps,
    const float* __restrict__ s_grav, const float* __restrict__ s_scc,
    const float* __restrict__ s_diss, const float* __restrict__ s_depo)
{
    #pragma clang fp contract(off)
    __shared__ float A[AR * WW];
    cg::grid_group grid = cg::this_grid();

    const int c = threadIdx.x;

    float rr    = fmaxf(s_rain_rate[0], 0.0f);
    float evapr = fmaxf(s_evap[0], 0.0f);
    float minhd = s_minhd[0];
    float heps  = s_heps[0];
    float gravr = fmaxf(s_grav[0], 0.0f);
    float sccr  = fmaxf(s_scc[0], 0.0f);
    float diss  = s_diss[0];
    float depo  = s_depo[0];

    #pragma unroll 1
    for (int g = 0; g < 5; ++g) {
        const bool FIRST = (g == 0), FINAL = (g == 4);
        // terrain ping-pong: in_terr->T1->T2->T1->T2->T0
        const float* tin; float* tout;
        if      (g == 0) { tin = tin0; tout = T1; }
        else if (g == 1) { tin = T1;   tout = T2; }
        else if (g == 2) { tin = T2;   tout = T1; }
        else if (g == 3) { tin = T1;   tout = T2; }
        else             { tin = T2;   tout = T0; }
        // s/w/v dbuf (guards intra-group neighbor race): A,A / A,B / B,A / A,B / B,-
        const bool inB  = (g == 2) || (g == 4);
        const bool outB = (g == 1) || (g == 3);
        const float* sin_ = inB ? sB : sA;
        const float* win_ = inB ? wB : wA;
        const float* vin_ = inB ? vB : vA;
        float* sout_ = outB ? sB : sA;
        float* wout_ = outB ? wB : wA;
        float* vout_ = outB ? vB : vA;
        const float* rain0 = rain_all + (size_t)(2 * g) * NPIX;
        const float* gno0  = gno_all  + (size_t)(2 * g) * NPIX;
        const float* rain1 = rain_all + (size_t)(2 * g + 1) * NPIX;
        const float* gno1  = gno_all  + (size_t)(2 * g + 1) * NPIX;

        #pragma unroll
        for (int t = 0; t < NTILE; ++t) {
            if (NTILE > 1 && t > 0) __syncthreads();  // drain epilogue A-reads
            const int tile = (int)blockIdx.x + t * (NBLK / NTILE);
            const int img  = tile >> 6;
            const int r0   = (tile & 63) * HH;
            run_group(FIRST, FINAL, tin + (size_t)img * NPIX, tout,
                      sin_, win_, vin_, sout_, wout_, vout_,
                      rain0, gno0, rain1, gno1,
                      rr, evapr, minhd, heps, gravr, sccr, diss, depo,
                      img, r0, c, A);
        }

        if (g < 4) grid.sync();   // device-scope fence: cross-XCD visibility
    }
}

extern "C" void kernel_launch(void* const* d_in, const int* in_sizes, int n_in,
                              void* d_out, int out_size, void* d_ws, size_t ws_size,
                              hipStream_t stream) {
    const float* in_terr    = (const float*)d_in[0];
    const float* rain_all   = (const float*)d_in[1];  // (1,10,W,W)
    const float* gnoise_all = (const float*)d_in[2];  // (1,10,W,W)
    const float* p_rr       = (const float*)d_in[3];
    const float* p_evap     = (const float*)d_in[4];
    const float* p_minhd    = (const float*)d_in[5];
    const float* p_heps     = (const float*)d_in[6];
    const float* p_grav     = (const float*)d_in[7];
    const float* p_scc      = (const float*)d_in[8];
    const float* p_diss     = (const float*)d_in[9];
    const float* p_depo     = (const float*)d_in[10];

    float* T0  = (float*)d_out;          // final output
    float* ws  = (float*)d_ws;
    float* T1  = ws;
    float* T2  = ws + (size_t)NTOT;
    float* sA  = ws + (size_t)2 * NTOT;
    float* wA  = ws + (size_t)3 * NTOT;
    float* vA  = ws + (size_t)4 * NTOT;
    const bool haveB = ws_size >= (size_t)8 * NTOT * sizeof(float);
    float* sB = haveB ? ws + (size_t)5 * NTOT : sA;
    float* wB = haveB ? ws + (size_t)6 * NTOT : wA;
    float* vB = haveB ? ws + (size_t)7 * NTOT : vA;

    // ---- path selection (host queries only, once; capture-safe) ----
    // 0 = 5-dispatch fallback, 1 = coop<1> (1024 blk), 2 = coop<2> (512 blk)
    static int s_path = -1;
    if (s_path < 0) {
        s_path = 0;
        int dev = 0;
        hipGetDevice(&dev);
        int coop = 0, ncu = 0;
        hipDeviceGetAttribute(&coop, hipDeviceAttributeCooperativeLaunch, dev);
        hipDeviceGetAttribute(&ncu, hipDeviceAttributeMultiprocessorCount, dev);
        if (coop && ncu > 0) {
            hipFuncAttributes fa{};
            int mb = 0;
            // try coop<1>: needs no scratch AND full 1024-block co-residency
            if (hipFuncGetAttributes(&fa,
                    reinterpret_cast<const void*>(&erosion_coop<1>)) == hipSuccess
                && fa.localSizeBytes == 0
                && hipOccupancyMaxActiveBlocksPerMultiprocessor(
                       &mb, erosion_coop<1>, 512, 0) == hipSuccess
                && (long)mb * ncu >= NBLK) {
                s_path = 1;
            } else {
                hipFuncAttributes fb{};
                int mb2 = 0;
                if (hipFuncGetAttributes(&fb,
                        reinterpret_cast<const void*>(&erosion_coop<2>)) == hipSuccess
                    && fb.localSizeBytes == 0
                    && hipOccupancyMaxActiveBlocksPerMultiprocessor(
                           &mb2, erosion_coop<2>, 512, 0) == hipSuccess
                    && (long)mb2 * ncu >= NBLK / 2) {
                    s_path = 2;
                }
            }
        }
    }

    if (haveB && s_path > 0) {
        void* args[] = {
            (void*)&in_terr, (void*)&T0, (void*)&T1, (void*)&T2,
            (void*)&sA, (void*)&wA, (void*)&vA,
            (void*)&sB, (void*)&wB, (void*)&vB,
            (void*)&rain_all, (void*)&gnoise_all,
            (void*)&p_rr, (void*)&p_evap, (void*)&p_minhd, (void*)&p_heps,
            (void*)&p_grav, (void*)&p_scc, (void*)&p_diss, (void*)&p_depo,
        };
        if (s_path == 1) {
            hipLaunchCooperativeKernel(erosion_coop<1>, dim3(NBLK), dim3(512),
                                       args, 0, stream);
        } else {
            hipLaunchCooperativeKernel(erosion_coop<2>, dim3(NBLK / 2), dim3(512),
                                       args, 0, stream);
        }
        return;
    }

    // ---- fallback: proven 5-dispatch path (r21 structure, 301.8us) ----
    dim3 grid(NBLK), block(512);
    #define RN(k) (rain_all   + (size_t)(k) * NPIX)
    #define GN(k) (gnoise_all + (size_t)(k) * NPIX)
    #define SCAL p_rr, p_evap, p_minhd, p_heps, p_grav, p_scc, p_diss, p_depo

    erosion_step<true, false><<<grid, block, 0, stream>>>(
        in_terr, T1, sA, wA, vA, sA, wA, vA, RN(0), GN(0), RN(1), GN(1), SCAL);
    erosion_step<false, false><<<grid, block, 0, stream>>>(
        T1, T2, sA, wA, vA, sB, wB, vB, RN(2), GN(2), RN(3), GN(3), SCAL);
    erosion_step<false, false><<<grid, block, 0, stream>>>(
        T2, T1, sB, wB, vB, sA, wA, vA, RN(4), GN(4), RN(5), GN(5), SCAL);
    erosion_step<false, false><<<grid, block, 0, stream>>>(
        T1, T2, sA, wA, vA, sB, wB, vB, RN(6), GN(6), RN(7), GN(7), SCAL);
    erosion_step<false, true><<<grid, block, 0, stream>>>(
        T2, T0, sB, wB, vB, sA, wA, vA, RN(8), GN(8), RN(9), GN(9), SCAL);

    #undef RN
    #undef GN
    #undef SCAL
}

// Round 10
// 313.020 us; speedup vs baseline: 1.0866x; 1.0866x over previous
//
#include <hip/hip_runtime.h>

// ErosionLayer: B=16, W=512, ITERS=10, fp32. PASSING numeric recipe (r5..r13,
// absmax 0.02734375): XLA-style greedy FMA via explicit fmaf() at exact sites,
// contract(off) elsewhere, correctly-rounded fp32 div/sqrt. cell_math op order
// is the frozen recipe -- only PROVABLY bit-exact simplifications allowed.
//
// History: r17 353.6 (s/w/v ping-pong dbuf kills inter-block race). r18 322.6
// (bit-exact DCE: factor==0 => rY/den dead; HH=8 ratio 1.25). r19/r20
// REGRESSED: forced VGPR cap 64 < live state -> scratch spill. r21 303.6:
// interleaved ph2 cut live state; no spill; 50.3us/dispatch; ~50us lost at
// dispatch boundaries. r22 301.8: single-barrier loop (ph2 at j=i-5) ran via
// the FALLBACK (coop gate failed: coop kernel at cap 85 used >64 VGPR ->
// occupancy 3 < 4). r23 REGRESSED 340: second coop gate design also never
// fired, and the co-compiled coop<1>/coop<2> instantiations perturbed
// erosion_step's regalloc (VGPR 28->36, FINAL dispatch 51->80us).
//
// r24 (this round): REVERT+BANK. Exactly the r22 fallback -- 5 dispatches of
// the single-barrier aliased kernel -- with ALL cooperative machinery deleted
// so the compilation unit has one kernel template and a clean regalloc
// context. No numeric or structural changes vs the measured-301.8 path.
//
// Kernel geometry: HH=8 owned rows/block; A = 16 LDS rows [r0-4, r0+11]
// (32 KiB; terrain-k retires in-place into slots 0..11, slot i = row r0-2+i);
// ONE barrier per loop iter (ph1 row i pre-barrier; slot-i write + ph2 row
// j=i-5 post-barrier; disjoint slots, stale slots clamped away at r0 edges);
// s/w/v ping-pong double-buffer across dispatches kills the inter-block halo
// race; grid 1024 = 4 blocks/CU co-resident; __launch_bounds__(512,6) (cap
// ~85: natural ~56-64, never spills). FINAL skips dead s/w/v stores.
#pragma clang fp contract(off)

constexpr int WW   = 512;
constexpr int NPIX = WW * WW;      // 2^18
constexpr int NTOT = 16 * NPIX;    // 4194304
constexpr int HH   = 8;            // owned rows per block
constexpr int AR   = 16;           // LDS rows [r0-4, r0+11]; terrain-k aliased
constexpr int BR   = 12;           // phase-1 computed rows [r0-2, r0+9]
constexpr int NBLK = 16 * (WW / HH);   // 1024

// FROZEN r5/r6 math (+ r18 provably-bit-exact factor/rY/den removal);
// all terrain reads from an LDS tile with row offset.
__device__ __forceinline__ void cell_math(
    const float* __restrict__ lds, int rowOfs, int r, int c,
    float rain_v, float gno_v,
    float rr, float evapr, float minhd, float heps, float gravr, float sccr,
    float diss, float depo,
    float& s_io, float& w_io, float& v_io, float& t_out, bool fin)
{
    #pragma clang fp contract(off)
    const float CELLW = 0.390625f;            // 200/512, exact

    float t_c = lds[(r - rowOfs) * WW + c];

    float w = fmaf(rr, rain_v, w_io);

    float dx, dy;
    if      (r == 0)      dx = 0.5f * fmaf(t_c, 1.1f, -t_c);
    else if (r == WW - 1) dx = 0.5f * fmaf(t_c, 0.9f, -t_c);
    else dx = 0.5f * (lds[(r + 1 - rowOfs) * WW + c] - lds[(r - 1 - rowOfs) * WW + c]);
    if      (c == 0)      dy = 0.5f * fmaf(t_c, 1.1f, -t_c);
    else if (c == WW - 1) dy = 0.5f * fmaf(t_c, 0.9f, -t_c);
    else dy = 0.5f * (lds[(r - rowOfs) * WW + c + 1] - lds[(r - rowOfs) * WW + c - 1]);

    float mag = sqrtf(fmaf(dx, dx, dy * dy) + 1e-11f);
    // r18 bit-exact DCE: mag >= sqrt(1e-11) = 3.16e-6 > 1e-10, so
    // factor = relu(1e-10 - mag) == 0, rY unused, den = mag + 0 = mag.
    // fmaf(0, rX, dx) == dx (sign-of-zero flip absorbed downstream).
    float fdx = dx / mag;                     // |fdx| <= 1 + ~3ulp
    float fdy = dy / mag;                     // |fdy| <= 1 + ~3ulp

    float fx  = (float)c + (-fdx);
    float fy  = (float)r + (-fdy);
    float x0f = floorf(fx), y0f = floorf(fy);
    float wx1 = fx - x0f;
    float wy1 = fy - y0f;
    int x0 = (int)x0f, y0 = (int)y0f;
    int x1 = x0 + 1,   y1 = y0 + 1;

    bool vx0 = (x0 >= 0) & (x0 < WW);
    bool vx1 = (x1 >= 0) & (x1 < WW);
    bool vy0 = (y0 >= 0) & (y0 < WW);
    bool vy1 = (y1 >= 0) & (y1 < WW);
    int x0c = min(max(x0, 0), WW - 1), x1c = min(max(x1, 0), WW - 1);
    int y0c = min(max(y0, 0), WW - 1), y1c = min(max(y1, 0), WW - 1);
    int ty0 = y0c - rowOfs, ty1 = y1c - rowOfs;   // in [r-2,r+2]-rowOfs

    float g00 = (vx0 && vy0) ? (lds[ty0 * WW + x0c] - 1.0f) : 0.0f;
    float g10 = (vx1 && vy0) ? (lds[ty0 * WW + x1c] - 1.0f) : 0.0f;
    float g01 = (vx0 && vy1) ? (lds[ty1 * WW + x0c] - 1.0f) : 0.0f;
    float g11 = (vx1 && vy1) ? (lds[ty1 * WW + x1c] - 1.0f) : 0.0f;

    float wx0 = 1.0f - wx1;
    float wy0 = 1.0f - wy1;
    float rowA = fmaf(wx0, g00, wx1 * g10);
    float rowB = fmaf(wx0, g01, wx1 * g11);
    float bil  = fmaf(wy0, rowA, wy1 * rowB);
    float neighbor = bil + 1.0f;

    float hd = t_c - neighbor;

    float v = v_io;
    float s = s_io;

    float hds  = ((hd - heps) > 0.0f) ? 1.0f : 0.0f;  // sign(relu(hd-eps))
    float nhd  = hds * fmaxf(hd, minhd);
    float q1 = nhd / CELLW;
    float q2 = q1 * v;
    float q3 = q2 * w;
    float sdiff = fmaf(-q3, sccr, s);                 // s - sed_cap
    float ftb   = (hd < 0.0f) ? 1.0f : 0.0f;          // relu(sign(-hd))
    float first = fminf(fmaxf(-hd, 0.0f), s);
    float ra = fmaxf(sdiff * depo, 0.0f);
    float rb = fmaxf((-sdiff) * diss, 0.0f);
    float deparg = fmaf(1.0f - ftb, ra - rb, first);
    float dep    = fmaxf(-fmaxf(hd, 0.0f), deparg);

    float s_new = s - dep;
    float t_new = t_c + dep;

    float rn = fmaxf(-fdy, 0.0f);
    float rm = fmaxf(1.0f - fabsf(fdy), 0.0f);
    float rp = fmaxf(fdy, 0.0f);

    float s1 = (c == WW - 1) ? 0.0f : rn * s_new;
    float s3 = (c == 0)      ? 0.0f : rp * s_new;
    s_io = fmaf(rm, s_new, s1) + s3;

    float w1 = (c == WW - 1) ? 0.0f : rn * w;
    float w3 = (c == 0)      ? 0.0f : rp * w;
    float wd = fmaf(rm, w, w1) + w3;
    w_io = wd * (1.0f - evapr);

    v_io = (gravr * hd) / CELLW;

    if (fin) {
        float aa = fmaf(-t_new, 2.0f, 1.0f);          // 1 - t*2 -> fnma
        float bq = 1.0f + aa;
        t_out = fmaxf(bq, 0.0f) - 1.0f;
    } else {
        t_out = t_new;
    }
}

// One 2-step group per dispatch. A = 16 LDS rows [r0-4, r0+11]; phase 1
// retires slot i -> terrain-k row r0-2+i; phase 2 deferred to j=i-5.
template <bool FIRST, bool FINAL>
__global__ __launch_bounds__(512, 6) void erosion_step(
    const float* __restrict__ tin, float* __restrict__ tout,
    const float* __restrict__ sed_in, const float* __restrict__ wat_in,
    const float* __restrict__ vel_in,
    float* __restrict__ sed_out, float* __restrict__ wat_out,
    float* __restrict__ vel_out,
    const float* __restrict__ rain0, const float* __restrict__ gno0,
    const float* __restrict__ rain1, const float* __restrict__ gno1,
    const float* __restrict__ s_rain_rate, const float* __restrict__ s_evap,
    const float* __restrict__ s_minhd, const float* __restrict__ s_heps,
    const float* __restrict__ s_grav, const float* __restrict__ s_scc,
    const float* __restrict__ s_diss, const float* __restrict__ s_depo)
{
    #pragma clang fp contract(off)
    __shared__ float A[AR * WW];

    const int c   = threadIdx.x;
    const int img = blockIdx.x >> 6;           // 64 tiles per image
    const int r0  = (blockIdx.x & 63) * HH;
    const float* tb = tin + (size_t)img * NPIX;
    const int gbase = img * NPIX + c;

    float rr    = fmaxf(s_rain_rate[0], 0.0f);
    float evapr = fmaxf(s_evap[0], 0.0f);
    float minhd = s_minhd[0];
    float heps  = s_heps[0];
    float gravr = fmaxf(s_grav[0], 0.0f);
    float sccr  = fmaxf(s_scc[0], 0.0f);
    float diss  = s_diss[0];
    float depo  = s_depo[0];

    // ---- stage terrain k-1 rows [r0-4, r0+11] (float4; transform if FIRST)
    // 4 groups of 128 threads; group rg loads rows {rg, rg+4, rg+8, rg+12};
    // 128 float4 = full 512-col row each. Exact cover of tile rows 0..15.
    {
        const int rg = c >> 7;               // 0..3
        const int c4 = (c & 127) << 2;       // column start (float4 aligned)
        #pragma unroll
        for (int j = 0; j < 4; ++j) {
            int ridx = j * 4 + rg;           // 0..15, each exactly once
            int y = r0 - 4 + ridx;
            if (y >= 0 && y < WW) {
                float4 v = *reinterpret_cast<const float4*>(tb + y * WW + c4);
                if (FIRST) {
                    v.x = (1.0f - v.x) / 2.0f;
                    v.y = (1.0f - v.y) / 2.0f;
                    v.z = (1.0f - v.z) / 2.0f;
                    v.w = (1.0f - v.w) / 2.0f;
                }
                *reinterpret_cast<float4*>(&A[ridx * WW + c4]) = v;
            }
        }
    }
    __syncthreads();

    // ---- fused loop, ONE barrier per iter. Iter i:
    //  (a) ph1 row x=r0-2+i (reads k-1 slots i..i+4)
    //  (b) barrier
    //  (c) write slot i (terrain-k) ; ph2 row j=i-5 (reads k slots i-5..i-1)
    // Proofs: slot i's last k-1 read is (a) of iter i, write at (c) after (b);
    // ph2's newest read (slot i-1, written iter i-1 (c)) is separated by (b)
    // of iter i; concurrent iter-i+1 (a) reads slots i+1..i+5, disjoint from
    // the slot-i write. sK[j] written iter j+2, read iter j+5. Stale slots
    // clamped away at r0=0 (slots 0,1) and r0=504 (slots 10,11) -- verified.
    float sK[HH], wK[HH], vK[HH];
    #pragma unroll
    for (int i = 0; i < BR; ++i) {
        const int x = r0 - 2 + i;
        const bool live1 = (x >= 0) && (x < WW);   // block-uniform
        float s0 = 0.0f, w0 = 0.0f, v0 = 0.0f, tn = 0.0f;
        if (live1) {
            if (!FIRST) {
                int g = gbase + x * WW;
                s0 = sed_in[g]; w0 = wat_in[g]; v0 = vel_in[g];
            }
            cell_math(A, r0 - 4, x, c, rain0[x * WW + c], gno0[x * WW + c],
                      rr, evapr, minhd, heps, gravr, sccr, diss, depo,
                      s0, w0, v0, tn, false);
        }
        __syncthreads();   // all k-1 reads of slot i complete block-wide
        if (live1) {
            A[i * WW + c] = tn;
            if (i >= 2 && i <= HH + 1) {        // owned rows: j = i-2 (const)
                sK[i - 2] = s0; wK[i - 2] = w0; vK[i - 2] = v0;
            }
        }
        if (i >= 5) {                           // ph2 row j = i-5 (0..6)
            const int j  = i - 5;
            const int x2 = r0 + j;              // always in [0, WW)
            float s2 = sK[j], w2 = wK[j], v2 = vK[j];
            float tn2;
            cell_math(A, r0 - 2, x2, c, rain1[x2 * WW + c], gno1[x2 * WW + c],
                      rr, evapr, minhd, heps, gravr, sccr, diss, depo,
                      s2, w2, v2, tn2, FINAL);
            int g = gbase + x2 * WW;
            tout[g] = tn2;
            if (!FINAL) { sed_out[g] = s2; wat_out[g] = w2; vel_out[g] = v2; }
        }
    }
    __syncthreads();       // slot 11 (written iter 11) visible block-wide

    // ---- epilogue: ph2 row j = 7 (reads k slots 7..11; at r0=504 clamps
    // keep unwritten slots 10,11 unread: y1c<=511 -> slot<=9)
    {
        const int j  = HH - 1;
        const int x2 = r0 + j;
        float s2 = sK[j], w2 = wK[j], v2 = vK[j];
        float tn2;
        cell_math(A, r0 - 2, x2, c, rain1[x2 * WW + c], gno1[x2 * WW + c],
                  rr, evapr, minhd, heps, gravr, sccr, diss, depo,
                  s2, w2, v2, tn2, FINAL);
        int g = gbase + x2 * WW;
        tout[g] = tn2;
        if (!FINAL) { sed_out[g] = s2; wat_out[g] = w2; vel_out[g] = v2; }
    }
}

extern "C" void kernel_launch(void* const* d_in, const int* in_sizes, int n_in,
                              void* d_out, int out_size, void* d_ws, size_t ws_size,
                              hipStream_t stream) {
    const float* in_terr    = (const float*)d_in[0];
    const float* rain_all   = (const float*)d_in[1];  // (1,10,W,W)
    const float* gnoise_all = (const float*)d_in[2];  // (1,10,W,W)
    const float* p_rr       = (const float*)d_in[3];
    const float* p_evap     = (const float*)d_in[4];
    const float* p_minhd    = (const float*)d_in[5];
    const float* p_heps     = (const float*)d_in[6];
    const float* p_grav     = (const float*)d_in[7];
    const float* p_scc      = (const float*)d_in[8];
    const float* p_diss     = (const float*)d_in[9];
    const float* p_depo     = (const float*)d_in[10];

    float* T0  = (float*)d_out;          // final output
    float* ws  = (float*)d_ws;
    float* T1  = ws;
    float* T2  = ws + (size_t)NTOT;
    float* sA  = ws + (size_t)2 * NTOT;
    float* wA  = ws + (size_t)3 * NTOT;
    float* vA  = ws + (size_t)4 * NTOT;
    const bool haveB = ws_size >= (size_t)8 * NTOT * sizeof(float);
    float* sB = haveB ? ws + (size_t)5 * NTOT : sA;
    float* wB = haveB ? ws + (size_t)6 * NTOT : wA;
    float* vB = haveB ? ws + (size_t)7 * NTOT : vA;

    dim3 grid(NBLK), block(512);
    #define RN(k) (rain_all   + (size_t)(k) * NPIX)
    #define GN(k) (gnoise_all + (size_t)(k) * NPIX)
    #define SCAL p_rr, p_evap, p_minhd, p_heps, p_grav, p_scc, p_diss, p_depo

    // steps 0+1: in_terr -> T1; s/w/v: (zeros) -> set A
    erosion_step<true, false><<<grid, block, 0, stream>>>(
        in_terr, T1, sA, wA, vA, sA, wA, vA, RN(0), GN(0), RN(1), GN(1), SCAL);
    // steps 2+3: T1 -> T2; s/w/v: A -> B
    erosion_step<false, false><<<grid, block, 0, stream>>>(
        T1, T2, sA, wA, vA, sB, wB, vB, RN(2), GN(2), RN(3), GN(3), SCAL);
    // steps 4+5: T2 -> T1; s/w/v: B -> A
    erosion_step<false, false><<<grid, block, 0, stream>>>(
        T2, T1, sB, wB, vB, sA, wA, vA, RN(4), GN(4), RN(5), GN(5), SCAL);
    // steps 6+7: T1 -> T2; s/w/v: A -> B
    erosion_step<false, false><<<grid, block, 0, stream>>>(
        T1, T2, sA, wA, vA, sB, wB, vB, RN(6), GN(6), RN(7), GN(7), SCAL);
    // steps 8+9: T2 -> T0 (= d_out), final transform; s/w/v: B -> (dead)
    erosion_step<false, true><<<grid, block, 0, stream>>>(
        T2, T0, sB, wB, vB, sA, wA, vA, RN(8), GN(8), RN(9), GN(9), SCAL);

    #undef RN
    #undef GN
    #undef SCAL
}

// Round 11
// 304.197 us; speedup vs baseline: 1.1182x; 1.0290x over previous
//
#include <hip/hip_runtime.h>

// ErosionLayer: B=16, W=512, ITERS=10, fp32. PASSING numeric recipe (r5..r13,
// absmax 0.02734375): XLA-style greedy FMA via explicit fmaf() at exact sites,
// contract(off) elsewhere, correctly-rounded fp32 div/sqrt. cell_math op order
// is the frozen recipe -- only PROVABLY bit-exact simplifications allowed.
//
// History: r17 353.6 (s/w/v ping-pong dbuf kills inter-block race). r18 322.6
// (bit-exact DCE + HH=8 ratio 1.25). r19/r20 REGRESSED: forced VGPR cap 64
// with a ~100+ live-set structure -> scratch spill. r21 303.6: interleaved
// ph2 (j=i-4) cut live state; 48-56 actual VGPR, no spill. r22 301.8:
// single-barrier loop (ph2 at j=i-5), 56-64 actual, no spill, Occ 55%,
// busy 85% (ran via fallback; coop gate never fired). r23 REGRESSED 340
// (coop co-compile perturbed regalloc). r24 313.0: clean unit, but allocator
// chose 72 actual VGPR (ILP preference, not need) -> 3 blocks/CU, Occ 42%,
// busy 79%, 52.6us/dispatch.
//
// r25 (this round): pin the register bucket. __launch_bounds__(512,8)
// (cap 64 actual). UNLIKE r19/r20 (whose paired/phase-split structure
// NEEDED ~100+ regs and spilled), THIS structure provably fits: r21
// measured 48-56 and r22 measured 56-64 actual, both WRITE=65536 (zero
// scratch). Forcing 64 re-runs regalloc under a satisfiable constraint ->
// recovers 4 blocks/CU (128 KiB LDS, 32 waves = 100% theoretical).
// Source is byte-identical to r24 except this one attribute.
// Spill tripwire at post-mortem: WRITE_SIZE must stay 65536 exactly.
//
// Kernel geometry: HH=8 owned rows/block; A = 16 LDS rows [r0-4, r0+11]
// (32 KiB; terrain-k retires in-place into slots 0..11, slot i = row r0-2+i);
// ONE barrier per loop iter (ph1 row i pre-barrier; slot-i write + ph2 row
// j=i-5 post-barrier; disjoint slots, stale slots clamped away at r0 edges);
// s/w/v ping-pong double-buffer across dispatches kills the inter-block halo
// race; grid 1024 = 4 blocks/CU co-resident. FINAL skips dead s/w/v stores.
#pragma clang fp contract(off)

constexpr int WW   = 512;
constexpr int NPIX = WW * WW;      // 2^18
constexpr int NTOT = 16 * NPIX;    // 4194304
constexpr int HH   = 8;            // owned rows per block
constexpr int AR   = 16;           // LDS rows [r0-4, r0+11]; terrain-k aliased
constexpr int BR   = 12;           // phase-1 computed rows [r0-2, r0+9]
constexpr int NBLK = 16 * (WW / HH);   // 1024

// FROZEN r5/r6 math (+ r18 provably-bit-exact factor/rY/den removal);
// all terrain reads from an LDS tile with row offset.
__device__ __forceinline__ void cell_math(
    const float* __restrict__ lds, int rowOfs, int r, int c,
    float rain_v, float gno_v,
    float rr, float evapr, float minhd, float heps, float gravr, float sccr,
    float diss, float depo,
    float& s_io, float& w_io, float& v_io, float& t_out, bool fin)
{
    #pragma clang fp contract(off)
    const float CELLW = 0.390625f;            // 200/512, exact

    float t_c = lds[(r - rowOfs) * WW + c];

    float w = fmaf(rr, rain_v, w_io);

    float dx, dy;
    if      (r == 0)      dx = 0.5f * fmaf(t_c, 1.1f, -t_c);
    else if (r == WW - 1) dx = 0.5f * fmaf(t_c, 0.9f, -t_c);
    else dx = 0.5f * (lds[(r + 1 - rowOfs) * WW + c] - lds[(r - 1 - rowOfs) * WW + c]);
    if      (c == 0)      dy = 0.5f * fmaf(t_c, 1.1f, -t_c);
    else if (c == WW - 1) dy = 0.5f * fmaf(t_c, 0.9f, -t_c);
    else dy = 0.5f * (lds[(r - rowOfs) * WW + c + 1] - lds[(r - rowOfs) * WW + c - 1]);

    float mag = sqrtf(fmaf(dx, dx, dy * dy) + 1e-11f);
    // r18 bit-exact DCE: mag >= sqrt(1e-11) = 3.16e-6 > 1e-10, so
    // factor = relu(1e-10 - mag) == 0, rY unused, den = mag + 0 = mag.
    // fmaf(0, rX, dx) == dx (sign-of-zero flip absorbed downstream).
    float fdx = dx / mag;                     // |fdx| <= 1 + ~3ulp
    float fdy = dy / mag;                     // |fdy| <= 1 + ~3ulp

    float fx  = (float)c + (-fdx);
    float fy  = (float)r + (-fdy);
    float x0f = floorf(fx), y0f = floorf(fy);
    float wx1 = fx - x0f;
    float wy1 = fy - y0f;
    int x0 = (int)x0f, y0 = (int)y0f;
    int x1 = x0 + 1,   y1 = y0 + 1;

    bool vx0 = (x0 >= 0) & (x0 < WW);
    bool vx1 = (x1 >= 0) & (x1 < WW);
    bool vy0 = (y0 >= 0) & (y0 < WW);
    bool vy1 = (y1 >= 0) & (y1 < WW);
    int x0c = min(max(x0, 0), WW - 1), x1c = min(max(x1, 0), WW - 1);
    int y0c = min(max(y0, 0), WW - 1), y1c = min(max(y1, 0), WW - 1);
    int ty0 = y0c - rowOfs, ty1 = y1c - rowOfs;   // in [r-2,r+2]-rowOfs

    float g00 = (vx0 && vy0) ? (lds[ty0 * WW + x0c] - 1.0f) : 0.0f;
    float g10 = (vx1 && vy0) ? (lds[ty0 * WW + x1c] - 1.0f) : 0.0f;
    float g01 = (vx0 && vy1) ? (lds[ty1 * WW + x0c] - 1.0f) : 0.0f;
    float g11 = (vx1 && vy1) ? (lds[ty1 * WW + x1c] - 1.0f) : 0.0f;

    float wx0 = 1.0f - wx1;
    float wy0 = 1.0f - wy1;
    float rowA = fmaf(wx0, g00, wx1 * g10);
    float rowB = fmaf(wx0, g01, wx1 * g11);
    float bil  = fmaf(wy0, rowA, wy1 * rowB);
    float neighbor = bil + 1.0f;

    float hd = t_c - neighbor;

    float v = v_io;
    float s = s_io;

    float hds  = ((hd - heps) > 0.0f) ? 1.0f : 0.0f;  // sign(relu(hd-eps))
    float nhd  = hds * fmaxf(hd, minhd);
    float q1 = nhd / CELLW;
    float q2 = q1 * v;
    float q3 = q2 * w;
    float sdiff = fmaf(-q3, sccr, s);                 // s - sed_cap
    float ftb   = (hd < 0.0f) ? 1.0f : 0.0f;          // relu(sign(-hd))
    float first = fminf(fmaxf(-hd, 0.0f), s);
    float ra = fmaxf(sdiff * depo, 0.0f);
    float rb = fmaxf((-sdiff) * diss, 0.0f);
    float deparg = fmaf(1.0f - ftb, ra - rb, first);
    float dep    = fmaxf(-fmaxf(hd, 0.0f), deparg);

    float s_new = s - dep;
    float t_new = t_c + dep;

    float rn = fmaxf(-fdy, 0.0f);
    float rm = fmaxf(1.0f - fabsf(fdy), 0.0f);
    float rp = fmaxf(fdy, 0.0f);

    float s1 = (c == WW - 1) ? 0.0f : rn * s_new;
    float s3 = (c == 0)      ? 0.0f : rp * s_new;
    s_io = fmaf(rm, s_new, s1) + s3;

    float w1 = (c == WW - 1) ? 0.0f : rn * w;
    float w3 = (c == 0)      ? 0.0f : rp * w;
    float wd = fmaf(rm, w, w1) + w3;
    w_io = wd * (1.0f - evapr);

    v_io = (gravr * hd) / CELLW;

    if (fin) {
        float aa = fmaf(-t_new, 2.0f, 1.0f);          // 1 - t*2 -> fnma
        float bq = 1.0f + aa;
        t_out = fmaxf(bq, 0.0f) - 1.0f;
    } else {
        t_out = t_new;
    }
}

// One 2-step group per dispatch. A = 16 LDS rows [r0-4, r0+11]; phase 1
// retires slot i -> terrain-k row r0-2+i; phase 2 deferred to j=i-5.
template <bool FIRST, bool FINAL>
__global__ __launch_bounds__(512, 8) void erosion_step(
    const float* __restrict__ tin, float* __restrict__ tout,
    const float* __restrict__ sed_in, const float* __restrict__ wat_in,
    const float* __restrict__ vel_in,
    float* __restrict__ sed_out, float* __restrict__ wat_out,
    float* __restrict__ vel_out,
    const float* __restrict__ rain0, const float* __restrict__ gno0,
    const float* __restrict__ rain1, const float* __restrict__ gno1,
    const float* __restrict__ s_rain_rate, const float* __restrict__ s_evap,
    const float* __restrict__ s_minhd, const float* __restrict__ s_heps,
    const float* __restrict__ s_grav, const float* __restrict__ s_scc,
    const float* __restrict__ s_diss, const float* __restrict__ s_depo)
{
    #pragma clang fp contract(off)
    __shared__ float A[AR * WW];

    const int c   = threadIdx.x;
    const int img = blockIdx.x >> 6;           // 64 tiles per image
    const int r0  = (blockIdx.x & 63) * HH;
    const float* tb = tin + (size_t)img * NPIX;
    const int gbase = img * NPIX + c;

    float rr    = fmaxf(s_rain_rate[0], 0.0f);
    float evapr = fmaxf(s_evap[0], 0.0f);
    float minhd = s_minhd[0];
    float heps  = s_heps[0];
    float gravr = fmaxf(s_grav[0], 0.0f);
    float sccr  = fmaxf(s_scc[0], 0.0f);
    float diss  = s_diss[0];
    float depo  = s_depo[0];

    // ---- stage terrain k-1 rows [r0-4, r0+11] (float4; transform if FIRST)
    // 4 groups of 128 threads; group rg loads rows {rg, rg+4, rg+8, rg+12};
    // 128 float4 = full 512-col row each. Exact cover of tile rows 0..15.
    {
        const int rg = c >> 7;               // 0..3
        const int c4 = (c & 127) << 2;       // column start (float4 aligned)
        #pragma unroll
        for (int j = 0; j < 4; ++j) {
            int ridx = j * 4 + rg;           // 0..15, each exactly once
            int y = r0 - 4 + ridx;
            if (y >= 0 && y < WW) {
                float4 v = *reinterpret_cast<const float4*>(tb + y * WW + c4);
                if (FIRST) {
                    v.x = (1.0f - v.x) / 2.0f;
                    v.y = (1.0f - v.y) / 2.0f;
                    v.z = (1.0f - v.z) / 2.0f;
                    v.w = (1.0f - v.w) / 2.0f;
                }
                *reinterpret_cast<float4*>(&A[ridx * WW + c4]) = v;
            }
        }
    }
    __syncthreads();

    // ---- fused loop, ONE barrier per iter. Iter i:
    //  (a) ph1 row x=r0-2+i (reads k-1 slots i..i+4)
    //  (b) barrier
    //  (c) write slot i (terrain-k) ; ph2 row j=i-5 (reads k slots i-5..i-1)
    // Proofs: slot i's last k-1 read is (a) of iter i, write at (c) after (b);
    // ph2's newest read (slot i-1, written iter i-1 (c)) is separated by (b)
    // of iter i; concurrent iter-i+1 (a) reads slots i+1..i+5, disjoint from
    // the slot-i write. sK[j] written iter j+2, read iter j+5. Stale slots
    // clamped away at r0=0 (slots 0,1) and r0=504 (slots 10,11) -- verified.
    float sK[HH], wK[HH], vK[HH];
    #pragma unroll
    for (int i = 0; i < BR; ++i) {
        const int x = r0 - 2 + i;
        const bool live1 = (x >= 0) && (x < WW);   // block-uniform
        float s0 = 0.0f, w0 = 0.0f, v0 = 0.0f, tn = 0.0f;
        if (live1) {
            if (!FIRST) {
                int g = gbase + x * WW;
                s0 = sed_in[g]; w0 = wat_in[g]; v0 = vel_in[g];
            }
            cell_math(A, r0 - 4, x, c, rain0[x * WW + c], gno0[x * WW + c],
                      rr, evapr, minhd, heps, gravr, sccr, diss, depo,
                      s0, w0, v0, tn, false);
        }
        __syncthreads();   // all k-1 reads of slot i complete block-wide
        if (live1) {
            A[i * WW + c] = tn;
            if (i >= 2 && i <= HH + 1) {        // owned rows: j = i-2 (const)
                sK[i - 2] = s0; wK[i - 2] = w0; vK[i - 2] = v0;
            }
        }
        if (i >= 5) {                           // ph2 row j = i-5 (0..6)
            const int j  = i - 5;
            const int x2 = r0 + j;              // always in [0, WW)
            float s2 = sK[j], w2 = wK[j], v2 = vK[j];
            float tn2;
            cell_math(A, r0 - 2, x2, c, rain1[x2 * WW + c], gno1[x2 * WW + c],
                      rr, evapr, minhd, heps, gravr, sccr, diss, depo,
                      s2, w2, v2, tn2, FINAL);
            int g = gbase + x2 * WW;
            tout[g] = tn2;
            if (!FINAL) { sed_out[g] = s2; wat_out[g] = w2; vel_out[g] = v2; }
        }
    }
    __syncthreads();       // slot 11 (written iter 11) visible block-wide

    // ---- epilogue: ph2 row j = 7 (reads k slots 7..11; at r0=504 clamps
    // keep unwritten slots 10,11 unread: y1c<=511 -> slot<=9)
    {
        const int j  = HH - 1;
        const int x2 = r0 + j;
        float s2 = sK[j], w2 = wK[j], v2 = vK[j];
        float tn2;
        cell_math(A, r0 - 2, x2, c, rain1[x2 * WW + c], gno1[x2 * WW + c],
                  rr, evapr, minhd, heps, gravr, sccr, diss, depo,
                  s2, w2, v2, tn2, FINAL);
        int g = gbase + x2 * WW;
        tout[g] = tn2;
        if (!FINAL) { sed_out[g] = s2; wat_out[g] = w2; vel_out[g] = v2; }
    }
}

extern "C" void kernel_launch(void* const* d_in, const int* in_sizes, int n_in,
                              void* d_out, int out_size, void* d_ws, size_t ws_size,
                              hipStream_t stream) {
    const float* in_terr    = (const float*)d_in[0];
    const float* rain_all   = (const float*)d_in[1];  // (1,10,W,W)
    const float* gnoise_all = (const float*)d_in[2];  // (1,10,W,W)
    const float* p_rr       = (const float*)d_in[3];
    const float* p_evap     = (const float*)d_in[4];
    const float* p_minhd    = (const float*)d_in[5];
    const float* p_heps     = (const float*)d_in[6];
    const float* p_grav     = (const float*)d_in[7];
    const float* p_scc      = (const float*)d_in[8];
    const float* p_diss     = (const float*)d_in[9];
    const float* p_depo     = (const float*)d_in[10];

    float* T0  = (float*)d_out;          // final output
    float* ws  = (float*)d_ws;
    float* T1  = ws;
    float* T2  = ws + (size_t)NTOT;
    float* sA  = ws + (size_t)2 * NTOT;
    float* wA  = ws + (size_t)3 * NTOT;
    float* vA  = ws + (size_t)4 * NTOT;
    const bool haveB = ws_size >= (size_t)8 * NTOT * sizeof(float);
    float* sB = haveB ? ws + (size_t)5 * NTOT : sA;
    float* wB = haveB ? ws + (size_t)6 * NTOT : wA;
    float* vB = haveB ? ws + (size_t)7 * NTOT : vA;

    dim3 grid(NBLK), block(512);
    #define RN(k) (rain_all   + (size_t)(k) * NPIX)
    #define GN(k) (gnoise_all + (size_t)(k) * NPIX)
    #define SCAL p_rr, p_evap, p_minhd, p_heps, p_grav, p_scc, p_diss, p_depo

    // steps 0+1: in_terr -> T1; s/w/v: (zeros) -> set A
    erosion_step<true, false><<<grid, block, 0, stream>>>(
        in_terr, T1, sA, wA, vA, sA, wA, vA, RN(0), GN(0), RN(1), GN(1), SCAL);
    // steps 2+3: T1 -> T2; s/w/v: A -> B
    erosion_step<false, false><<<grid, block, 0, stream>>>(
        T1, T2, sA, wA, vA, sB, wB, vB, RN(2), GN(2), RN(3), GN(3), SCAL);
    // steps 4+5: T2 -> T1; s/w/v: B -> A
    erosion_step<false, false><<<grid, block, 0, stream>>>(
        T2, T1, sB, wB, vB, sA, wA, vA, RN(4), GN(4), RN(5), GN(5), SCAL);
    // steps 6+7: T1 -> T2; s/w/v: A -> B
    erosion_step<false, false><<<grid, block, 0, stream>>>(
        T1, T2, sA, wA, vA, sB, wB, vB, RN(6), GN(6), RN(7), GN(7), SCAL);
    // steps 8+9: T2 -> T0 (= d_out), final transform; s/w/v: B -> (dead)
    erosion_step<false, true><<<grid, block, 0, stream>>>(
        T2, T0, sB, wB, vB, sA, wA, vA, RN(8), GN(8), RN(9), GN(9), SCAL);

    #undef RN
    #undef GN
    #undef SCAL
}